// Round 15
// baseline (122.646 us; speedup 1.0000x reference)
//
#include <hip/hip_runtime.h>
#include <hip/hip_bf16.h>

#define BATCH 8
#define LTOK 1280
#define DIMC 192
#define HEADS 6
#define KD 32
#define HID 768
#define NROWS (BATCH*LTOK)   // 10240

typedef short s16x8 __attribute__((ext_vector_type(8)));
typedef float f32x4 __attribute__((ext_vector_type(4)));
typedef unsigned short u16;

// q pre-scale: 32^-0.5 * log2(e)  (softmax runs in exp2 domain)
#define QS (0.17677669529663687f * 1.4426950408889634f)
#define L2E 1.4426950408889634f

__device__ __forceinline__ u16 f2bf(float x) {
    unsigned u = __float_as_uint(x);
    u = (u + 0x7FFFu + ((u >> 16) & 1u)) >> 16;
    return (u16)u;
}
__device__ __forceinline__ float bf2f(u16 v) { return __uint_as_float((unsigned)v << 16); }
__device__ __forceinline__ float bflo(unsigned u) { return __uint_as_float(u << 16); }
__device__ __forceinline__ float bfhi(unsigned u) { return __uint_as_float(u & 0xffff0000u); }
__device__ __forceinline__ float fexp2(float x) { float r; asm("v_exp_f32 %0, %1" : "=v"(r) : "v"(x)); return r; }
__device__ __forceinline__ float frcp(float x)  { float r; asm("v_rcp_f32 %0, %1" : "=v"(r) : "v"(x)); return r; }

// --- pre_a: ONLY what QKV needs — wqkv transpose + LN1 ---------------------
__global__ __launch_bounds__(256) void pre_a(const float* __restrict__ w0,
                                             u16* __restrict__ o0,
                                             const float* __restrict__ xz,
                                             const float* __restrict__ ln1g,
                                             const float* __restrict__ ln1b,
                                             u16* __restrict__ hbuf) {
    __shared__ float s[16][17];
    int f = blockIdx.x;
    if (f >= 432) {                        // LN1
        int row = (f - 432) * 4 + (threadIdx.x >> 6);
        int lane = threadIdx.x & 63;
        const float* xr = xz + (size_t)row * DIMC;
        float v0 = xr[lane], v1 = xr[lane + 64], v2 = xr[lane + 128];
        float sm = v0 + v1 + v2;
        float ss = v0 * v0 + v1 * v1 + v2 * v2;
        #pragma unroll
        for (int off = 32; off; off >>= 1) {
            sm += __shfl_xor(sm, off);
            ss += __shfl_xor(ss, off);
        }
        float mu  = sm * (1.0f / DIMC);
        float var = ss * (1.0f / DIMC) - mu * mu;
        float inv = rsqrtf(var + 1e-5f);
        u16* yr = hbuf + (size_t)row * DIMC;
        yr[lane]       = f2bf((v0 - mu) * inv * ln1g[lane]       + ln1b[lane]);
        yr[lane + 64]  = f2bf((v1 - mu) * inv * ln1g[lane + 64]  + ln1b[lane + 64]);
        yr[lane + 128] = f2bf((v2 - mu) * inv * ln1g[lane + 128] + ln1b[lane + 128]);
        return;
    }
    int tn = f % 36, tk = f / 36;
    int tx = threadIdx.x & 15, ty = threadIdx.x >> 4;
    s[ty][tx] = w0[(size_t)(tk * 16 + ty) * 576 + tn * 16 + tx];
    __syncthreads();
    o0[(size_t)(tn * 16 + ty) * 192 + tk * 16 + tx] = f2bf(s[tx][ty]);
}

// --- qkv_mega: QKV GEMM + fragment-packed bias matrix + late wtrans --------
__global__ __launch_bounds__(256) void qkv_mega(const u16* __restrict__ A,
                                                const u16* __restrict__ Wt,
                                                const float* __restrict__ bias,
                                                u16* __restrict__ qb,
                                                u16* __restrict__ kp,
                                                u16* __restrict__ vp,
                                                const int* __restrict__ bidx,
                                                const float* __restrict__ btab,
                                                int n_off, u16* __restrict__ bmp,
                                                const float* __restrict__ wp,
                                                const float* __restrict__ wf1,
                                                const float* __restrict__ wf2,
                                                u16* __restrict__ op,
                                                u16* __restrict__ of1,
                                                u16* __restrict__ of2) {
    int bid = blockIdx.x;
    if (bid >= 9960) {                     // late weight transposes
        __shared__ float s[16][17];
        int f2 = bid - 9960;
        const float* in; u16* out; int K, N, tn, tk;
        if (f2 < 144)      { in = wp;  out = op;  K = 192; N = 192; tn = f2 % 12; tk = f2 / 12; }
        else if (f2 < 720) { in = wf1; out = of1; K = 192; N = 768; int q = f2 - 144; tn = q % 48; tk = q / 48; }
        else               { in = wf2; out = of2; K = 768; N = 192; int q = f2 - 720; tn = q % 12; tk = q / 12; }
        int tx = threadIdx.x & 15, ty = threadIdx.x >> 4;
        s[ty][tx] = in[(size_t)(tk * 16 + ty) * N + tn * 16 + tx];
        __syncthreads();
        out[(size_t)(tn * 16 + ty) * K + tk * 16 + tx] = f2bf(s[tx][ty]);
        return;
    }
    if (bid >= 360) {                      // fragment-packed bias matrix
        int fb = bid - 360;                // (qt, T) major, h minor
        int qt = fb / 120;
        int rem = fb - qt * 120;
        int T = rem / 6, h = rem - (rem / 6) * 6;
        int tid = threadIdx.x;
        int half = tid >> 7, L = (tid >> 1) & 63, j4 = (tid & 1) * 4;
        int n = qt * 16 + (L & 15);
        int m = T * 64 + half * 32 + ((L >> 4) << 3) + j4;
        int4 iv = *(const int4*)(bidx + (size_t)n * LTOK + m);
        const float* tab = btab + (size_t)h * n_off;
        ushort4 o;
        o.x = f2bf(tab[iv.x] * L2E);
        o.y = f2bf(tab[iv.y] * L2E);
        o.z = f2bf(tab[iv.z] * L2E);
        o.w = f2bf(tab[iv.w] * L2E);
        *(ushort4*)(bmp + (size_t)(h * 80 + qt) * 20480 + T * 1024 + tid * 4) = o;
        return;
    }
    // ---- QKV GEMM: MTILE=256, K=192, N=576 ----
    int bx = bid % 9, by = bid / 9;
    int tid = threadIdx.x;
    int L = tid & 63, w = tid >> 6;
    int r = L & 15, g = L >> 4;
    int m0 = by * 256 + w * 64;
    int n0 = bx * 64;

    f32x4 acc[4][4] = {};
    const u16* Ab = A + (size_t)(m0 + r) * 192 + g * 8;
    const u16* Wb = Wt + (size_t)(n0 + r) * 192 + g * 8;
    #pragma unroll 6
    for (int k0 = 0; k0 < 192; k0 += 32) {
        s16x8 af[4];
        #pragma unroll
        for (int mi = 0; mi < 4; ++mi)
            af[mi] = *(const s16x8*)(Ab + (size_t)mi * 16 * 192 + k0);
        #pragma unroll
        for (int nn = 0; nn < 4; ++nn) {
            s16x8 bf = *(const s16x8*)(Wb + (size_t)nn * 16 * 192 + k0);
            #pragma unroll
            for (int mi = 0; mi < 4; ++mi)
                acc[mi][nn] = __builtin_amdgcn_mfma_f32_16x16x32_bf16(af[mi], bf, acc[mi][nn], 0, 0, 0);
        }
    }
    #pragma unroll
    for (int mi = 0; mi < 4; ++mi)
    #pragma unroll
    for (int nn = 0; nn < 4; ++nn) {
        int cb = n0 + nn * 16;
        int h  = cb / 96, c0 = cb % 96;
        int reg = c0 >> 5;                 // 0=q, 1=k, 2=v
        #pragma unroll
        for (int i = 0; i < 4; ++i) {
            int row = m0 + mi * 16 + g * 4 + i;
            float v = acc[mi][nn][i] + bias[cb + r];
            if (reg == 0) {
                v *= QS;
                qb[(size_t)row * DIMC + h * 32 + (c0 & 31) + r] = f2bf(v);
            } else {
                int b_ = row / LTOK, t = row - b_ * LTOK;
                int T = t >> 5, it = t & 31;
                int d = (c0 & 31) + r;
                if (reg == 1) {
                    int which = (it >> 2) & 1;
                    int ik = ((it >> 3) << 2) | (it & 3);
                    int Lk = ((d >> 3) << 4) + ik;
                    kp[((size_t)(b_ * HEADS + h) * 40 + T) * 1024 + which * 512 + Lk * 8 + (d & 7)] = f2bf(v);
                } else {
                    int Lv = ((it >> 3) << 4) + (d & 15);
                    vp[((size_t)(b_ * HEADS + h) * 40 + T) * 1024 + (d >> 4) * 512 + Lv * 8 + (it & 7)] = f2bf(v);
                }
            }
        }
    }
}

// ---- MFMA flash attention: in-block split-K, 8 waves, QK-ahead pipeline ---
// 960 blocks = (b 8) x (h 6) x (qg 20), XCD-chunk swizzled. 512 threads:
// wave w -> q-tile qw=w&3, key-half kh=w>>2 (keys [kh*640, kh*640+640)).
// 10 iterations of 64 keys each, 1 barrier/iter (was 20). Final cross-half
// merge through LDS (kvs reused as float scratch).
__global__ __launch_bounds__(512) void attn_mfma(const u16* __restrict__ qb,
                                                 const u16* __restrict__ kp,
                                                 const u16* __restrict__ vp,
                                                 const u16* __restrict__ bmp,
                                                 u16* __restrict__ ob) {
    __shared__ __align__(16) u16 kvs[2][2][2][2048];  // [dbuf][kh][k/v][2 tiles] 32KB
    int tid = threadIdx.x;
    int L = tid & 63, w = tid >> 6;
    int r = L & 15, g = L >> 4;
    int L8 = L * 8;
    int qw = w & 3, kh = w >> 2;

    int bid = blockIdx.x;
    int work = (bid & 7) * 120 + (bid >> 3);     // 960 = 8 * 120
    int b  = work & 7;
    int hq = work >> 3;                          // 0..119
    int qt = (hq % 20) * 4 + qw;                 // 16-row q-tile, 0..79
    int h  = hq / 20;

    s16x8 qf = *(const s16x8*)(qb + (size_t)(b * LTOK + qt * 16 + r) * DIMC + h * 32 + g * 8);

    // staging: wave w stages (half shalf, stream skv, tile stile); 2KB/iter
    int shalf = w >> 2, skv = (w >> 1) & 1, stile = w & 1;
    const u16* gs = (skv ? vp : kp) + (size_t)(b * HEADS + h) * 40 * 1024
                    + (size_t)(shalf * 20 + stile) * 1024 + L8;
    u16* dst0 = &kvs[0][shalf][skv][stile * 1024 + L8];
    u16* dst1 = &kvs[1][shalf][skv][stile * 1024 + L8];

    // fragment-packed bias, this wave's key-half
    const u16* bmr = bmp + (size_t)(h * 80 + qt) * 20480 + (size_t)kh * 10 * 1024 + L8;

    f32x4 acc0 = {0.f, 0.f, 0.f, 0.f}, acc1 = {0.f, 0.f, 0.f, 0.f};
    float lsum = 0.f;

    // prologue: stage tile-pair 0 -> buf0; bias pair 0
    {
        int4 pA = *(const int4*)(gs);
        int4 pB = *(const int4*)(gs + 512);
        *(int4*)dst0 = pA;
        *(int4*)(dst0 + 512) = pB;
    }
    int4 cb0 = *(const int4*)(bmr);
    int4 cb1 = *(const int4*)(bmr + 512);
    __syncthreads();

    f32x4 s0, s1, s2, s3;
    {
        const u16* kb = &kvs[0][kh][0][0];
        f32x4 z0, z1, z2, z3;
        z0[0] = bflo(cb0.x); z0[1] = bfhi(cb0.x); z0[2] = bflo(cb0.y); z0[3] = bfhi(cb0.y);
        z1[0] = bflo(cb0.z); z1[1] = bfhi(cb0.z); z1[2] = bflo(cb0.w); z1[3] = bfhi(cb0.w);
        z2[0] = bflo(cb1.x); z2[1] = bfhi(cb1.x); z2[2] = bflo(cb1.y); z2[3] = bfhi(cb1.y);
        z3[0] = bflo(cb1.z); z3[1] = bfhi(cb1.z); z3[2] = bflo(cb1.w); z3[3] = bfhi(cb1.w);
        s16x8 kf0 = *(const s16x8*)(kb + L8);
        s16x8 kf1 = *(const s16x8*)(kb + 512 + L8);
        s16x8 kf2 = *(const s16x8*)(kb + 1024 + L8);
        s16x8 kf3 = *(const s16x8*)(kb + 1536 + L8);
        s0 = __builtin_amdgcn_mfma_f32_16x16x32_bf16(kf0, qf, z0, 0, 0, 0);
        s1 = __builtin_amdgcn_mfma_f32_16x16x32_bf16(kf1, qf, z1, 0, 0, 0);
        s2 = __builtin_amdgcn_mfma_f32_16x16x32_bf16(kf2, qf, z2, 0, 0, 0);
        s3 = __builtin_amdgcn_mfma_f32_16x16x32_bf16(kf3, qf, z3, 0, 0, 0);
    }

    #pragma unroll 1
    for (int T = 0; T < 10; ++T) {
        int4 nA, nB, nb0, nb1;
        if (T < 9) {
            nA  = *(const int4*)(gs + (size_t)(2 * T + 2) * 1024);
            nB  = *(const int4*)(gs + (size_t)(2 * T + 2) * 1024 + 512);
            nb0 = *(const int4*)(bmr + (size_t)(T + 1) * 1024);
            nb1 = *(const int4*)(bmr + (size_t)(T + 1) * 1024 + 512);
        }
        __builtin_amdgcn_s_setprio(1);
        float p[16];
        #pragma unroll
        for (int j = 0; j < 4; ++j) {
            p[j]      = fexp2(s0[j]);
            p[4 + j]  = fexp2(s1[j]);
            p[8 + j]  = fexp2(s2[j]);
            p[12 + j] = fexp2(s3[j]);
        }
        float t0 = ((p[0] + p[1]) + (p[2] + p[3])) + ((p[4] + p[5]) + (p[6] + p[7]));
        float t1 = ((p[8] + p[9]) + (p[10] + p[11])) + ((p[12] + p[13]) + (p[14] + p[15]));
        lsum += t0 + t1;
        union { unsigned u[4]; s16x8 v; } pa, pb;
        #pragma unroll
        for (int j = 0; j < 4; ++j) {
            asm("v_cvt_pk_bf16_f32 %0, %1, %2" : "=v"(pa.u[j]) : "v"(p[2 * j]), "v"(p[2 * j + 1]));
            asm("v_cvt_pk_bf16_f32 %0, %1, %2" : "=v"(pb.u[j]) : "v"(p[8 + 2 * j]), "v"(p[9 + 2 * j]));
        }
        const u16* vb = &kvs[T & 1][kh][1][0];
        s16x8 v0 = *(const s16x8*)(vb + L8);
        s16x8 v1 = *(const s16x8*)(vb + 512 + L8);
        s16x8 v2 = *(const s16x8*)(vb + 1024 + L8);
        s16x8 v3 = *(const s16x8*)(vb + 1536 + L8);
        acc0 = __builtin_amdgcn_mfma_f32_16x16x32_bf16(pa.v, v0, acc0, 0, 0, 0);
        acc1 = __builtin_amdgcn_mfma_f32_16x16x32_bf16(pa.v, v1, acc1, 0, 0, 0);
        acc0 = __builtin_amdgcn_mfma_f32_16x16x32_bf16(pb.v, v2, acc0, 0, 0, 0);
        acc1 = __builtin_amdgcn_mfma_f32_16x16x32_bf16(pb.v, v3, acc1, 0, 0, 0);
        __builtin_amdgcn_s_setprio(0);

        if (T < 9) {
            u16* d = (T & 1) ? dst0 : dst1;      // buf[(T+1)&1]
            *(int4*)d = nA;
            *(int4*)(d + 512) = nB;
        }
        __syncthreads();
        if (T < 9) {
            const u16* kb = &kvs[(T + 1) & 1][kh][0][0];
            f32x4 z0, z1, z2, z3;
            z0[0] = bflo(nb0.x); z0[1] = bfhi(nb0.x); z0[2] = bflo(nb0.y); z0[3] = bfhi(nb0.y);
            z1[0] = bflo(nb0.z); z1[1] = bfhi(nb0.z); z1[2] = bflo(nb0.w); z1[3] = bfhi(nb0.w);
            z2[0] = bflo(nb1.x); z2[1] = bfhi(nb1.x); z2[2] = bflo(nb1.y); z2[3] = bfhi(nb1.y);
            z3[0] = bflo(nb1.z); z3[1] = bfhi(nb1.z); z3[2] = bflo(nb1.w); z3[3] = bfhi(nb1.w);
            s16x8 kf0 = *(const s16x8*)(kb + L8);
            s16x8 kf1 = *(const s16x8*)(kb + 512 + L8);
            s16x8 kf2 = *(const s16x8*)(kb + 1024 + L8);
            s16x8 kf3 = *(const s16x8*)(kb + 1536 + L8);
            __builtin_amdgcn_s_setprio(1);
            s0 = __builtin_amdgcn_mfma_f32_16x16x32_bf16(kf0, qf, z0, 0, 0, 0);
            s1 = __builtin_amdgcn_mfma_f32_16x16x32_bf16(kf1, qf, z1, 0, 0, 0);
            s2 = __builtin_amdgcn_mfma_f32_16x16x32_bf16(kf2, qf, z2, 0, 0, 0);
            s3 = __builtin_amdgcn_mfma_f32_16x16x32_bf16(kf3, qf, z3, 0, 0, 0);
            __builtin_amdgcn_s_setprio(0);
        }
    }

    // cross-half merge: kh=1 partials -> LDS (kvs reused) -> kh=0 adds
    float* red = (float*)&kvs[0][0][0][0];
    if (kh == 1) {
        float* rd = red + (size_t)(qw * 64 + L) * 9;
        rd[0] = acc0[0]; rd[1] = acc0[1]; rd[2] = acc0[2]; rd[3] = acc0[3];
        rd[4] = acc1[0]; rd[5] = acc1[1]; rd[6] = acc1[2]; rd[7] = acc1[3];
        rd[8] = lsum;
    }
    __syncthreads();
    if (kh == 0) {
        const float* rd = red + (size_t)(qw * 64 + L) * 9;
        acc0[0] += rd[0]; acc0[1] += rd[1]; acc0[2] += rd[2]; acc0[3] += rd[3];
        acc1[0] += rd[4]; acc1[1] += rd[5]; acc1[2] += rd[6]; acc1[3] += rd[7];
        float lr = lsum + rd[8];
        lr += __shfl_xor(lr, 16);
        lr += __shfl_xor(lr, 32);
        #pragma unroll
        for (int i = 0; i < 4; ++i) {
            float linv = frcp(__shfl(lr, 4 * g + i));
            size_t orow = (size_t)(b * LTOK + qt * 16 + 4 * g + i) * DIMC + h * 32 + r;
            ob[orow]      = f2bf(acc0[i] * linv);
            ob[orow + 16] = f2bf(acc1[i] * linv);
        }
    }
}

// ---------------- MFMA GEMM: C = act(A@W + bias) (+R)  --------------------
// A bf16 [M][K] row-major, Wt bf16 [N][K]. 256 thr = 4 waves.
template<int ACT, int RES, int OBF, int K, int MTILE>
__global__ __launch_bounds__(256) void gemm_mfma(const u16* __restrict__ A,
                                                 const u16* __restrict__ Wt,
                                                 const float* __restrict__ bias,
                                                 const float* __restrict__ R,
                                                 void* __restrict__ Cp,
                                                 int N) {
    constexpr int SUB = MTILE / 64;
    int tid = threadIdx.x;
    int L = tid & 63, w = tid >> 6;
    int r = L & 15, g = L >> 4;
    int m0 = blockIdx.y * MTILE + w * (16 * SUB);
    int n0 = blockIdx.x * 64;

    f32x4 acc[SUB][4] = {};
    const u16* Ab = A + (size_t)(m0 + r) * K + g * 8;
    const u16* Wb = Wt + (size_t)(n0 + r) * K + g * 8;
    #pragma unroll 6
    for (int k0 = 0; k0 < K; k0 += 32) {
        s16x8 af[SUB];
        #pragma unroll
        for (int mi = 0; mi < SUB; ++mi)
            af[mi] = *(const s16x8*)(Ab + (size_t)mi * 16 * K + k0);
        #pragma unroll
        for (int nn = 0; nn < 4; ++nn) {
            s16x8 bf = *(const s16x8*)(Wb + (size_t)nn * 16 * K + k0);
            #pragma unroll
            for (int mi = 0; mi < SUB; ++mi)
                acc[mi][nn] = __builtin_amdgcn_mfma_f32_16x16x32_bf16(af[mi], bf, acc[mi][nn], 0, 0, 0);
        }
    }

    #pragma unroll
    for (int mi = 0; mi < SUB; ++mi)
    #pragma unroll
    for (int nn = 0; nn < 4; ++nn) {
        int cb = n0 + nn * 16;
        #pragma unroll
        for (int i = 0; i < 4; ++i) {
            int row = m0 + mi * 16 + g * 4 + i;
            float v = acc[mi][nn][i] + bias[cb + r];
            if (ACT == 1) {
                float u = v;
                float y = 0.7978845608028654f * (u + 0.044715f * u * u * u);
                float e2 = fexp2(y * 2.885390081777927f);   // 2*log2(e)
                v = u - u * frcp(e2 + 1.0f);                // 0.5u(1+tanh(y))
            }
            if (RES) v += R[(size_t)row * N + cb + r];
            if (OBF) ((u16*)Cp)[(size_t)row * N + cb + r] = f2bf(v);
            else     ((float*)Cp)[(size_t)row * N + cb + r] = v;
        }
    }
}

// ------- Depthwise 3x3 conv + BN + LayerNorm2 fused (wave per row) ---------
// xm is bf16 (proj output); writes xm2 f32 (fc2 residual) + hbuf bf16 (fc1 in)
__global__ __launch_bounds__(256) void conv_ln_kernel(const u16* __restrict__ xm,
                                                      const float* __restrict__ w,
                                                      const float* __restrict__ scale,
                                                      const float* __restrict__ bias,
                                                      const float* __restrict__ g2,
                                                      const float* __restrict__ b2,
                                                      float* __restrict__ xm2,
                                                      u16* __restrict__ y) {
    int row = blockIdx.x * 4 + (threadIdx.x >> 6);
    int lane = threadIdx.x & 63;
    int b = row / LTOK, t = row - b * LTOK;
    int H, W, base, y0, x0;
    if (t < 1024) { H = 32; W = 32; base = 0;    y0 = t >> 5;            x0 = t & 31; }
    else          { H = 16; W = 16; base = 1024; int tt = t - 1024; y0 = tt >> 4; x0 = tt & 15; }
    float a0 = 0.f, a1 = 0.f, a2 = 0.f;
    #pragma unroll
    for (int ky = 0; ky < 3; ++ky) {
        int yy = y0 + ky - 1;
        if (yy < 0 || yy >= H) continue;
        #pragma unroll
        for (int kx = 0; kx < 3; ++kx) {
            int xx = x0 + kx - 1;
            if (xx < 0 || xx >= W) continue;
            const u16* xr = xm + (size_t)(b * LTOK + base + yy * W + xx) * DIMC;
            const float* wr = w + (ky * 3 + kx) * DIMC;
            a0 += wr[lane]       * bf2f(xr[lane]);
            a1 += wr[lane + 64]  * bf2f(xr[lane + 64]);
            a2 += wr[lane + 128] * bf2f(xr[lane + 128]);
        }
    }
    float v0 = a0 * scale[lane]       + bias[lane];
    float v1 = a1 * scale[lane + 64]  + bias[lane + 64];
    float v2 = a2 * scale[lane + 128] + bias[lane + 128];
    float* xr2 = xm2 + (size_t)row * DIMC;
    xr2[lane] = v0; xr2[lane + 64] = v1; xr2[lane + 128] = v2;
    float s = v0 + v1 + v2;
    float ss = v0 * v0 + v1 * v1 + v2 * v2;
    #pragma unroll
    for (int off = 32; off; off >>= 1) {
        s  += __shfl_xor(s, off);
        ss += __shfl_xor(ss, off);
    }
    float mu  = s * (1.0f / DIMC);
    float var = ss * (1.0f / DIMC) - mu * mu;
    float inv = rsqrtf(var + 1e-5f);
    u16* yr = y + (size_t)row * DIMC;
    yr[lane]       = f2bf((v0 - mu) * inv * g2[lane]       + b2[lane]);
    yr[lane + 64]  = f2bf((v1 - mu) * inv * g2[lane + 64]  + b2[lane + 64]);
    yr[lane + 128] = f2bf((v2 - mu) * inv * g2[lane + 128] + b2[lane + 128]);
}

// ---------------------------------------------------------------------------
extern "C" void kernel_launch(void* const* d_in, const int* in_sizes, int n_in,
                              void* d_out, int out_size, void* d_ws, size_t ws_size,
                              hipStream_t stream) {
    const float* xz       = (const float*)d_in[0];
    const int*   bidx     = (const int*)  d_in[1];
    const float* ln1_g    = (const float*)d_in[2];
    const float* ln1_b    = (const float*)d_in[3];
    const float* wqkv     = (const float*)d_in[4];
    const float* bqkv     = (const float*)d_in[5];
    const float* wproj    = (const float*)d_in[6];
    const float* bproj    = (const float*)d_in[7];
    const float* btab     = (const float*)d_in[8];
    const float* conv_w   = (const float*)d_in[9];
    const float* bn_scale = (const float*)d_in[10];
    const float* bn_bias  = (const float*)d_in[11];
    const float* ln2_g    = (const float*)d_in[12];
    const float* ln2_b    = (const float*)d_in[13];
    const float* w1       = (const float*)d_in[14];
    const float* b1       = (const float*)d_in[15];
    const float* w2       = (const float*)d_in[16];
    const float* b2       = (const float*)d_in[17];
    int n_off = in_sizes[8] / HEADS;
    float* out = (float*)d_out;

    // ---- workspace layout (bytes), liveness overlays; peak 40.2 MB ----
    char* wsb = (char*)d_ws;
    u16*  hbuf   = (u16*)(wsb + 0);                    // LN1/LN2 out; ob overlays
    u16*  ob     = (u16*)(wsb + 0);
    u16*  wqkvT  = (u16*)(wsb + 3932160);
    u16*  wprojT = (u16*)(wsb + 4153344);
    u16*  w1T    = (u16*)(wsb + 4227072);
    u16*  w2T    = (u16*)(wsb + 4521984);
    u16*  bmp    = (u16*)(wsb + 4816896);              // 19.6 MB; hid overlays
    u16*  hid    = (u16*)(wsb + 4816896);
    u16*  kp     = (u16*)(wsb + 24477696);
    u16*  vp     = (u16*)(wsb + 28409856);
    float* xm2   = (float*)(wsb + 24477696);           // overlays kp/vp (dead)
    u16*  qb     = (u16*)(wsb + 32342016);
    u16*  xm     = (u16*)(wsb + 32342016);             // bf16; overlays qb (dead)

    // 1) minimal critical-path prefix: wqkv transpose + LN1
    pre_a<<<432 + NROWS / 4, 256, 0, stream>>>(wqkv, wqkvT, xz, ln1_g, ln1_b, hbuf);
    // 2) QKV GEMM + bias-matrix pack + late weight transposes (one launch)
    qkv_mega<<<11256, 256, 0, stream>>>(
        hbuf, wqkvT, bqkv, qb, kp, vp,
        bidx, btab, n_off, bmp,
        wproj, w1, w2, wprojT, w1T, w2T);
    // 3) attention (in-block split-K, 8 waves, dbuf LDS, XCD-swizzled)
    attn_mfma<<<960, 512, 0, stream>>>(qb, kp, vp, bmp, ob);
    // 4) proj + residual(xz) -> xm bf16
    gemm_mfma<0,1,1,DIMC,128><<<dim3(DIMC / 64, NROWS / 128), 256, 0, stream>>>(
        ob, wprojT, bproj, xz, xm, DIMC);
    // 5) depthwise conv + BN + LN2 -> xm2 f32 + hbuf bf16
    conv_ln_kernel<<<NROWS / 4, 256, 0, stream>>>(
        xm, conv_w, bn_scale, bn_bias, ln2_g, ln2_b, xm2, hbuf);
    // 6) MLP fc1 + GELU (MTILE=256) -> hid bf16
    gemm_mfma<1,0,1,DIMC,256><<<dim3(HID / 64, NROWS / 256), 256, 0, stream>>>(
        hbuf, w1T, b1, nullptr, hid, HID);
    // 7) MLP fc2 + residual(xm2) -> out f32
    gemm_mfma<0,1,0,HID,128><<<dim3(DIMC / 64, NROWS / 128), 256, 0, stream>>>(
        hid, w2T, b2, xm2, out, DIMC);
}

// Round 16
// 119.985 us; speedup vs baseline: 1.0222x; 1.0222x over previous
//
#include <hip/hip_runtime.h>
#include <hip/hip_bf16.h>

#define BATCH 8
#define LTOK 1280
#define DIMC 192
#define HEADS 6
#define KD 32
#define HID 768
#define NROWS (BATCH*LTOK)   // 10240

typedef short s16x8 __attribute__((ext_vector_type(8)));
typedef float f32x4 __attribute__((ext_vector_type(4)));
typedef unsigned short u16;

// q pre-scale: 32^-0.5 * log2(e)  (softmax runs in exp2 domain)
#define QS (0.17677669529663687f * 1.4426950408889634f)
#define L2E 1.4426950408889634f

__device__ __forceinline__ u16 f2bf(float x) {
    unsigned u = __float_as_uint(x);
    u = (u + 0x7FFFu + ((u >> 16) & 1u)) >> 16;
    return (u16)u;
}
__device__ __forceinline__ float bf2f(u16 v) { return __uint_as_float((unsigned)v << 16); }
__device__ __forceinline__ float bflo(unsigned u) { return __uint_as_float(u << 16); }
__device__ __forceinline__ float bfhi(unsigned u) { return __uint_as_float(u & 0xffff0000u); }
__device__ __forceinline__ float fexp2(float x) { float r; asm("v_exp_f32 %0, %1" : "=v"(r) : "v"(x)); return r; }
__device__ __forceinline__ float frcp(float x)  { float r; asm("v_rcp_f32 %0, %1" : "=v"(r) : "v"(x)); return r; }

// --- pre_a: ONLY what QKV needs — wqkv transpose + LN1 ---------------------
__global__ __launch_bounds__(256) void pre_a(const float* __restrict__ w0,
                                             u16* __restrict__ o0,
                                             const float* __restrict__ xz,
                                             const float* __restrict__ ln1g,
                                             const float* __restrict__ ln1b,
                                             u16* __restrict__ hbuf) {
    __shared__ float s[16][17];
    int f = blockIdx.x;
    if (f >= 432) {                        // LN1
        int row = (f - 432) * 4 + (threadIdx.x >> 6);
        int lane = threadIdx.x & 63;
        const float* xr = xz + (size_t)row * DIMC;
        float v0 = xr[lane], v1 = xr[lane + 64], v2 = xr[lane + 128];
        float sm = v0 + v1 + v2;
        float ss = v0 * v0 + v1 * v1 + v2 * v2;
        #pragma unroll
        for (int off = 32; off; off >>= 1) {
            sm += __shfl_xor(sm, off);
            ss += __shfl_xor(ss, off);
        }
        float mu  = sm * (1.0f / DIMC);
        float var = ss * (1.0f / DIMC) - mu * mu;
        float inv = rsqrtf(var + 1e-5f);
        u16* yr = hbuf + (size_t)row * DIMC;
        yr[lane]       = f2bf((v0 - mu) * inv * ln1g[lane]       + ln1b[lane]);
        yr[lane + 64]  = f2bf((v1 - mu) * inv * ln1g[lane + 64]  + ln1b[lane + 64]);
        yr[lane + 128] = f2bf((v2 - mu) * inv * ln1g[lane + 128] + ln1b[lane + 128]);
        return;
    }
    int tn = f % 36, tk = f / 36;
    int tx = threadIdx.x & 15, ty = threadIdx.x >> 4;
    s[ty][tx] = w0[(size_t)(tk * 16 + ty) * 576 + tn * 16 + tx];
    __syncthreads();
    o0[(size_t)(tn * 16 + ty) * 192 + tk * 16 + tx] = f2bf(s[tx][ty]);
}

// --- qkv_mega: QKV GEMM + fragment-packed bias matrix + late wtrans --------
__global__ __launch_bounds__(256) void qkv_mega(const u16* __restrict__ A,
                                                const u16* __restrict__ Wt,
                                                const float* __restrict__ bias,
                                                u16* __restrict__ qb,
                                                u16* __restrict__ kp,
                                                u16* __restrict__ vp,
                                                const int* __restrict__ bidx,
                                                const float* __restrict__ btab,
                                                int n_off, u16* __restrict__ bmp,
                                                const float* __restrict__ wp,
                                                const float* __restrict__ wf1,
                                                const float* __restrict__ wf2,
                                                u16* __restrict__ op,
                                                u16* __restrict__ of1,
                                                u16* __restrict__ of2) {
    int bid = blockIdx.x;
    if (bid >= 9960) {                     // late weight transposes
        __shared__ float s[16][17];
        int f2 = bid - 9960;
        const float* in; u16* out; int K, N, tn, tk;
        if (f2 < 144)      { in = wp;  out = op;  K = 192; N = 192; tn = f2 % 12; tk = f2 / 12; }
        else if (f2 < 720) { in = wf1; out = of1; K = 192; N = 768; int q = f2 - 144; tn = q % 48; tk = q / 48; }
        else               { in = wf2; out = of2; K = 768; N = 192; int q = f2 - 720; tn = q % 12; tk = q / 12; }
        int tx = threadIdx.x & 15, ty = threadIdx.x >> 4;
        s[ty][tx] = in[(size_t)(tk * 16 + ty) * N + tn * 16 + tx];
        __syncthreads();
        out[(size_t)(tn * 16 + ty) * K + tk * 16 + tx] = f2bf(s[tx][ty]);
        return;
    }
    if (bid >= 360) {                      // fragment-packed bias matrix
        int fb = bid - 360;                // (qt, T) major, h minor
        int qt = fb / 120;
        int rem = fb - qt * 120;
        int T = rem / 6, h = rem - (rem / 6) * 6;
        int tid = threadIdx.x;
        int half = tid >> 7, L = (tid >> 1) & 63, j4 = (tid & 1) * 4;
        int n = qt * 16 + (L & 15);
        int m = T * 64 + half * 32 + ((L >> 4) << 3) + j4;
        int4 iv = *(const int4*)(bidx + (size_t)n * LTOK + m);
        const float* tab = btab + (size_t)h * n_off;
        ushort4 o;
        o.x = f2bf(tab[iv.x] * L2E);
        o.y = f2bf(tab[iv.y] * L2E);
        o.z = f2bf(tab[iv.z] * L2E);
        o.w = f2bf(tab[iv.w] * L2E);
        *(ushort4*)(bmp + (size_t)(h * 80 + qt) * 20480 + T * 1024 + tid * 4) = o;
        return;
    }
    // ---- QKV GEMM: MTILE=256, K=192, N=576 ----
    int bx = bid % 9, by = bid / 9;
    int tid = threadIdx.x;
    int L = tid & 63, w = tid >> 6;
    int r = L & 15, g = L >> 4;
    int m0 = by * 256 + w * 64;
    int n0 = bx * 64;

    f32x4 acc[4][4] = {};
    const u16* Ab = A + (size_t)(m0 + r) * 192 + g * 8;
    const u16* Wb = Wt + (size_t)(n0 + r) * 192 + g * 8;
    #pragma unroll 6
    for (int k0 = 0; k0 < 192; k0 += 32) {
        s16x8 af[4];
        #pragma unroll
        for (int mi = 0; mi < 4; ++mi)
            af[mi] = *(const s16x8*)(Ab + (size_t)mi * 16 * 192 + k0);
        #pragma unroll
        for (int nn = 0; nn < 4; ++nn) {
            s16x8 bf = *(const s16x8*)(Wb + (size_t)nn * 16 * 192 + k0);
            #pragma unroll
            for (int mi = 0; mi < 4; ++mi)
                acc[mi][nn] = __builtin_amdgcn_mfma_f32_16x16x32_bf16(af[mi], bf, acc[mi][nn], 0, 0, 0);
        }
    }
    #pragma unroll
    for (int mi = 0; mi < 4; ++mi)
    #pragma unroll
    for (int nn = 0; nn < 4; ++nn) {
        int cb = n0 + nn * 16;
        int h  = cb / 96, c0 = cb % 96;
        int reg = c0 >> 5;                 // 0=q, 1=k, 2=v
        #pragma unroll
        for (int i = 0; i < 4; ++i) {
            int row = m0 + mi * 16 + g * 4 + i;
            float v = acc[mi][nn][i] + bias[cb + r];
            if (reg == 0) {
                v *= QS;
                qb[(size_t)row * DIMC + h * 32 + (c0 & 31) + r] = f2bf(v);
            } else {
                int b_ = row / LTOK, t = row - b_ * LTOK;
                int T = t >> 5, it = t & 31;
                int d = (c0 & 31) + r;
                if (reg == 1) {
                    int which = (it >> 2) & 1;
                    int ik = ((it >> 3) << 2) | (it & 3);
                    int Lk = ((d >> 3) << 4) + ik;
                    kp[((size_t)(b_ * HEADS + h) * 40 + T) * 1024 + which * 512 + Lk * 8 + (d & 7)] = f2bf(v);
                } else {
                    int Lv = ((it >> 3) << 4) + (d & 15);
                    vp[((size_t)(b_ * HEADS + h) * 40 + T) * 1024 + (d >> 4) * 512 + Lv * 8 + (it & 7)] = f2bf(v);
                }
            }
        }
    }
}

// ---- MFMA flash attention: LDS K/V, 64-key iters, QK-ahead pipeline -------
// Softmax denominator computed on the MFMA pipe: one extra PV-style MFMA per
// 32-key tile with B = all-ones bf16 gives accl[i] = sum_k P[q=4g+i][k] over
// ALL keys — zero per-iter VALU adds and no end-of-loop shuffles.
__global__ __launch_bounds__(256) void attn_mfma(const u16* __restrict__ qb,
                                                 const u16* __restrict__ kp,
                                                 const u16* __restrict__ vp,
                                                 const u16* __restrict__ bmp,
                                                 u16* __restrict__ ob) {
    __shared__ __align__(16) u16 kvs[2][2][2048];   // [dbuf][k/v][2 tiles] 16KB
    int tid = threadIdx.x;
    int L = tid & 63, w = tid >> 6;
    int r = L & 15, g = L >> 4;
    int L8 = L * 8;

    int bid = blockIdx.x;
    int work = (bid & 7) * 120 + (bid >> 3);     // 960 = 8 * 120
    int b  = work & 7;
    int hq = work >> 3;                          // 0..119
    int qt = (hq % 20) * 4 + w;                  // 16-row q-tile, 0..79
    int h  = hq / 20;

    s16x8 qf = *(const s16x8*)(qb + (size_t)(b * LTOK + qt * 16 + r) * DIMC + h * 32 + g * 8);

    int skv = w >> 1, half = w & 1;
    const u16* gs = (skv ? vp : kp) + (size_t)(b * HEADS + h) * 40 * 1024 + L8;
    u16* dst0 = &kvs[0][skv][half * 1024 + L8];
    u16* dst1 = &kvs[1][skv][half * 1024 + L8];

    const u16* bmr = bmp + (size_t)(h * 80 + qt) * 20480 + L8;   // fragment-packed

    f32x4 acc0 = {0.f, 0.f, 0.f, 0.f}, acc1 = {0.f, 0.f, 0.f, 0.f};
    f32x4 accl = {0.f, 0.f, 0.f, 0.f};
    s16x8 ones;
    #pragma unroll
    for (int j = 0; j < 8; ++j) ones[j] = (short)0x3F80;   // bf16 1.0

    {
        int4 pA = *(const int4*)(gs + half * 1024);
        int4 pB = *(const int4*)(gs + half * 1024 + 512);
        *(int4*)dst0 = pA;
        *(int4*)(dst0 + 512) = pB;
    }
    int4 cb0 = *(const int4*)(bmr);
    int4 cb1 = *(const int4*)(bmr + 512);
    __syncthreads();

    f32x4 s0, s1, s2, s3;
    {
        const u16* kb = &kvs[0][0][0];
        f32x4 z0, z1, z2, z3;
        z0[0] = bflo(cb0.x); z0[1] = bfhi(cb0.x); z0[2] = bflo(cb0.y); z0[3] = bfhi(cb0.y);
        z1[0] = bflo(cb0.z); z1[1] = bfhi(cb0.z); z1[2] = bflo(cb0.w); z1[3] = bfhi(cb0.w);
        z2[0] = bflo(cb1.x); z2[1] = bfhi(cb1.x); z2[2] = bflo(cb1.y); z2[3] = bfhi(cb1.y);
        z3[0] = bflo(cb1.z); z3[1] = bfhi(cb1.z); z3[2] = bflo(cb1.w); z3[3] = bfhi(cb1.w);
        s16x8 kf0 = *(const s16x8*)(kb + L8);
        s16x8 kf1 = *(const s16x8*)(kb + 512 + L8);
        s16x8 kf2 = *(const s16x8*)(kb + 1024 + L8);
        s16x8 kf3 = *(const s16x8*)(kb + 1536 + L8);
        s0 = __builtin_amdgcn_mfma_f32_16x16x32_bf16(kf0, qf, z0, 0, 0, 0);
        s1 = __builtin_amdgcn_mfma_f32_16x16x32_bf16(kf1, qf, z1, 0, 0, 0);
        s2 = __builtin_amdgcn_mfma_f32_16x16x32_bf16(kf2, qf, z2, 0, 0, 0);
        s3 = __builtin_amdgcn_mfma_f32_16x16x32_bf16(kf3, qf, z3, 0, 0, 0);
    }

    #pragma unroll 1
    for (int T = 0; T < 20; ++T) {
        int4 nA, nB, nb0, nb1;
        if (T < 19) {
            nA  = *(const int4*)(gs + (size_t)(2 * T + 2 + half) * 1024);
            nB  = *(const int4*)(gs + (size_t)(2 * T + 2 + half) * 1024 + 512);
            nb0 = *(const int4*)(bmr + (size_t)(T + 1) * 1024);
            nb1 = *(const int4*)(bmr + (size_t)(T + 1) * 1024 + 512);
        }
        __builtin_amdgcn_s_setprio(1);
        float p[16];
        #pragma unroll
        for (int j = 0; j < 4; ++j) {
            p[j]      = fexp2(s0[j]);
            p[4 + j]  = fexp2(s1[j]);
            p[8 + j]  = fexp2(s2[j]);
            p[12 + j] = fexp2(s3[j]);
        }
        union { unsigned u[4]; s16x8 v; } pa, pb;
        #pragma unroll
        for (int j = 0; j < 4; ++j) {
            asm("v_cvt_pk_bf16_f32 %0, %1, %2" : "=v"(pa.u[j]) : "v"(p[2 * j]), "v"(p[2 * j + 1]));
            asm("v_cvt_pk_bf16_f32 %0, %1, %2" : "=v"(pb.u[j]) : "v"(p[8 + 2 * j]), "v"(p[9 + 2 * j]));
        }
        const u16* vb = &kvs[T & 1][1][0];
        s16x8 v0 = *(const s16x8*)(vb + L8);
        s16x8 v1 = *(const s16x8*)(vb + 512 + L8);
        s16x8 v2 = *(const s16x8*)(vb + 1024 + L8);
        s16x8 v3 = *(const s16x8*)(vb + 1536 + L8);
        acc0 = __builtin_amdgcn_mfma_f32_16x16x32_bf16(pa.v, v0, acc0, 0, 0, 0);
        acc1 = __builtin_amdgcn_mfma_f32_16x16x32_bf16(pa.v, v1, acc1, 0, 0, 0);
        accl = __builtin_amdgcn_mfma_f32_16x16x32_bf16(pa.v, ones, accl, 0, 0, 0);
        acc0 = __builtin_amdgcn_mfma_f32_16x16x32_bf16(pb.v, v2, acc0, 0, 0, 0);
        acc1 = __builtin_amdgcn_mfma_f32_16x16x32_bf16(pb.v, v3, acc1, 0, 0, 0);
        accl = __builtin_amdgcn_mfma_f32_16x16x32_bf16(pb.v, ones, accl, 0, 0, 0);
        __builtin_amdgcn_s_setprio(0);

        if (T < 19) {
            u16* d = (T & 1) ? dst0 : dst1;      // buf[(T+1)&1]
            *(int4*)d = nA;
            *(int4*)(d + 512) = nB;
        }
        __syncthreads();
        if (T < 19) {
            const u16* kb = &kvs[(T + 1) & 1][0][0];
            f32x4 z0, z1, z2, z3;
            z0[0] = bflo(nb0.x); z0[1] = bfhi(nb0.x); z0[2] = bflo(nb0.y); z0[3] = bfhi(nb0.y);
            z1[0] = bflo(nb0.z); z1[1] = bfhi(nb0.z); z1[2] = bflo(nb0.w); z1[3] = bfhi(nb0.w);
            z2[0] = bflo(nb1.x); z2[1] = bfhi(nb1.x); z2[2] = bflo(nb1.y); z2[3] = bfhi(nb1.y);
            z3[0] = bflo(nb1.z); z3[1] = bfhi(nb1.z); z3[2] = bflo(nb1.w); z3[3] = bfhi(nb1.w);
            s16x8 kf0 = *(const s16x8*)(kb + L8);
            s16x8 kf1 = *(const s16x8*)(kb + 512 + L8);
            s16x8 kf2 = *(const s16x8*)(kb + 1024 + L8);
            s16x8 kf3 = *(const s16x8*)(kb + 1536 + L8);
            __builtin_amdgcn_s_setprio(1);
            s0 = __builtin_amdgcn_mfma_f32_16x16x32_bf16(kf0, qf, z0, 0, 0, 0);
            s1 = __builtin_amdgcn_mfma_f32_16x16x32_bf16(kf1, qf, z1, 0, 0, 0);
            s2 = __builtin_amdgcn_mfma_f32_16x16x32_bf16(kf2, qf, z2, 0, 0, 0);
            s3 = __builtin_amdgcn_mfma_f32_16x16x32_bf16(kf3, qf, z3, 0, 0, 0);
            __builtin_amdgcn_s_setprio(0);
        }
    }

    #pragma unroll
    for (int i = 0; i < 4; ++i) {
        float linv = frcp(accl[i]);
        size_t orow = (size_t)(b * LTOK + qt * 16 + 4 * g + i) * DIMC + h * 32 + r;
        ob[orow]      = f2bf(acc0[i] * linv);
        ob[orow + 16] = f2bf(acc1[i] * linv);
    }
}

// ---------------- MFMA GEMM: C = act(A@W + bias) (+R)  --------------------
// A bf16 [M][K] row-major, Wt bf16 [N][K]. 256 thr = 4 waves.
template<int ACT, int RES, int OBF, int K, int MTILE>
__global__ __launch_bounds__(256) void gemm_mfma(const u16* __restrict__ A,
                                                 const u16* __restrict__ Wt,
                                                 const float* __restrict__ bias,
                                                 const float* __restrict__ R,
                                                 void* __restrict__ Cp,
                                                 int N) {
    constexpr int SUB = MTILE / 64;
    int tid = threadIdx.x;
    int L = tid & 63, w = tid >> 6;
    int r = L & 15, g = L >> 4;
    int m0 = blockIdx.y * MTILE + w * (16 * SUB);
    int n0 = blockIdx.x * 64;

    f32x4 acc[SUB][4] = {};
    const u16* Ab = A + (size_t)(m0 + r) * K + g * 8;
    const u16* Wb = Wt + (size_t)(n0 + r) * K + g * 8;
    #pragma unroll 6
    for (int k0 = 0; k0 < K; k0 += 32) {
        s16x8 af[SUB];
        #pragma unroll
        for (int mi = 0; mi < SUB; ++mi)
            af[mi] = *(const s16x8*)(Ab + (size_t)mi * 16 * K + k0);
        #pragma unroll
        for (int nn = 0; nn < 4; ++nn) {
            s16x8 bf = *(const s16x8*)(Wb + (size_t)nn * 16 * K + k0);
            #pragma unroll
            for (int mi = 0; mi < SUB; ++mi)
                acc[mi][nn] = __builtin_amdgcn_mfma_f32_16x16x32_bf16(af[mi], bf, acc[mi][nn], 0, 0, 0);
        }
    }

    #pragma unroll
    for (int mi = 0; mi < SUB; ++mi)
    #pragma unroll
    for (int nn = 0; nn < 4; ++nn) {
        int cb = n0 + nn * 16;
        #pragma unroll
        for (int i = 0; i < 4; ++i) {
            int row = m0 + mi * 16 + g * 4 + i;
            float v = acc[mi][nn][i] + bias[cb + r];
            if (ACT == 1) {
                float u = v;
                float y = 0.7978845608028654f * (u + 0.044715f * u * u * u);
                float e2 = fexp2(y * 2.885390081777927f);   // 2*log2(e)
                v = u - u * frcp(e2 + 1.0f);                // 0.5u(1+tanh(y))
            }
            if (RES) v += R[(size_t)row * N + cb + r];
            if (OBF) ((u16*)Cp)[(size_t)row * N + cb + r] = f2bf(v);
            else     ((float*)Cp)[(size_t)row * N + cb + r] = v;
        }
    }
}

// ------- Depthwise 3x3 conv + BN + LayerNorm2 fused (wave per row) ---------
// xm is bf16 (proj output); writes xm2 f32 (fc2 residual) + hbuf bf16 (fc1 in)
__global__ __launch_bounds__(256) void conv_ln_kernel(const u16* __restrict__ xm,
                                                      const float* __restrict__ w,
                                                      const float* __restrict__ scale,
                                                      const float* __restrict__ bias,
                                                      const float* __restrict__ g2,
                                                      const float* __restrict__ b2,
                                                      float* __restrict__ xm2,
                                                      u16* __restrict__ y) {
    int row = blockIdx.x * 4 + (threadIdx.x >> 6);
    int lane = threadIdx.x & 63;
    int b = row / LTOK, t = row - b * LTOK;
    int H, W, base, y0, x0;
    if (t < 1024) { H = 32; W = 32; base = 0;    y0 = t >> 5;            x0 = t & 31; }
    else          { H = 16; W = 16; base = 1024; int tt = t - 1024; y0 = tt >> 4; x0 = tt & 15; }
    float a0 = 0.f, a1 = 0.f, a2 = 0.f;
    #pragma unroll
    for (int ky = 0; ky < 3; ++ky) {
        int yy = y0 + ky - 1;
        if (yy < 0 || yy >= H) continue;
        #pragma unroll
        for (int kx = 0; kx < 3; ++kx) {
            int xx = x0 + kx - 1;
            if (xx < 0 || xx >= W) continue;
            const u16* xr = xm + (size_t)(b * LTOK + base + yy * W + xx) * DIMC;
            const float* wr = w + (ky * 3 + kx) * DIMC;
            a0 += wr[lane]       * bf2f(xr[lane]);
            a1 += wr[lane + 64]  * bf2f(xr[lane + 64]);
            a2 += wr[lane + 128] * bf2f(xr[lane + 128]);
        }
    }
    float v0 = a0 * scale[lane]       + bias[lane];
    float v1 = a1 * scale[lane + 64]  + bias[lane + 64];
    float v2 = a2 * scale[lane + 128] + bias[lane + 128];
    float* xr2 = xm2 + (size_t)row * DIMC;
    xr2[lane] = v0; xr2[lane + 64] = v1; xr2[lane + 128] = v2;
    float s = v0 + v1 + v2;
    float ss = v0 * v0 + v1 * v1 + v2 * v2;
    #pragma unroll
    for (int off = 32; off; off >>= 1) {
        s  += __shfl_xor(s, off);
        ss += __shfl_xor(ss, off);
    }
    float mu  = s * (1.0f / DIMC);
    float var = ss * (1.0f / DIMC) - mu * mu;
    float inv = rsqrtf(var + 1e-5f);
    u16* yr = y + (size_t)row * DIMC;
    yr[lane]       = f2bf((v0 - mu) * inv * g2[lane]       + b2[lane]);
    yr[lane + 64]  = f2bf((v1 - mu) * inv * g2[lane + 64]  + b2[lane + 64]);
    yr[lane + 128] = f2bf((v2 - mu) * inv * g2[lane + 128] + b2[lane + 128]);
}

// ---------------------------------------------------------------------------
extern "C" void kernel_launch(void* const* d_in, const int* in_sizes, int n_in,
                              void* d_out, int out_size, void* d_ws, size_t ws_size,
                              hipStream_t stream) {
    const float* xz       = (const float*)d_in[0];
    const int*   bidx     = (const int*)  d_in[1];
    const float* ln1_g    = (const float*)d_in[2];
    const float* ln1_b    = (const float*)d_in[3];
    const float* wqkv     = (const float*)d_in[4];
    const float* bqkv     = (const float*)d_in[5];
    const float* wproj    = (const float*)d_in[6];
    const float* bproj    = (const float*)d_in[7];
    const float* btab     = (const float*)d_in[8];
    const float* conv_w   = (const float*)d_in[9];
    const float* bn_scale = (const float*)d_in[10];
    const float* bn_bias  = (const float*)d_in[11];
    const float* ln2_g    = (const float*)d_in[12];
    const float* ln2_b    = (const float*)d_in[13];
    const float* w1       = (const float*)d_in[14];
    const float* b1       = (const float*)d_in[15];
    const float* w2       = (const float*)d_in[16];
    const float* b2       = (const float*)d_in[17];
    int n_off = in_sizes[8] / HEADS;
    float* out = (float*)d_out;

    // ---- workspace layout (bytes), liveness overlays; peak 40.2 MB ----
    char* wsb = (char*)d_ws;
    u16*  hbuf   = (u16*)(wsb + 0);                    // LN1/LN2 out; ob overlays
    u16*  ob     = (u16*)(wsb + 0);
    u16*  wqkvT  = (u16*)(wsb + 3932160);
    u16*  wprojT = (u16*)(wsb + 4153344);
    u16*  w1T    = (u16*)(wsb + 4227072);
    u16*  w2T    = (u16*)(wsb + 4521984);
    u16*  bmp    = (u16*)(wsb + 4816896);              // 19.6 MB; hid overlays
    u16*  hid    = (u16*)(wsb + 4816896);
    u16*  kp     = (u16*)(wsb + 24477696);
    u16*  vp     = (u16*)(wsb + 28409856);
    float* xm2   = (float*)(wsb + 24477696);           // overlays kp/vp (dead)
    u16*  qb     = (u16*)(wsb + 32342016);
    u16*  xm     = (u16*)(wsb + 32342016);             // bf16; overlays qb (dead)

    // 1) minimal critical-path prefix: wqkv transpose + LN1
    pre_a<<<432 + NROWS / 4, 256, 0, stream>>>(wqkv, wqkvT, xz, ln1_g, ln1_b, hbuf);
    // 2) QKV GEMM + bias-matrix pack + late weight transposes (one launch)
    qkv_mega<<<11256, 256, 0, stream>>>(
        hbuf, wqkvT, bqkv, qb, kp, vp,
        bidx, btab, n_off, bmp,
        wproj, w1, w2, wprojT, w1T, w2T);
    // 3) attention (QK-ahead pipeline, MFMA-computed denominator)
    attn_mfma<<<960, 256, 0, stream>>>(qb, kp, vp, bmp, ob);
    // 4) proj + residual(xz) -> xm bf16
    gemm_mfma<0,1,1,DIMC,128><<<dim3(DIMC / 64, NROWS / 128), 256, 0, stream>>>(
        ob, wprojT, bproj, xz, xm, DIMC);
    // 5) depthwise conv + BN + LN2 -> xm2 f32 + hbuf bf16
    conv_ln_kernel<<<NROWS / 4, 256, 0, stream>>>(
        xm, conv_w, bn_scale, bn_bias, ln2_g, ln2_b, xm2, hbuf);
    // 6) MLP fc1 + GELU (MTILE=256) -> hid bf16
    gemm_mfma<1,0,1,DIMC,256><<<dim3(HID / 64, NROWS / 256), 256, 0, stream>>>(
        hbuf, w1T, b1, nullptr, hid, HID);
    // 7) MLP fc2 + residual(xm2) -> out f32
    gemm_mfma<0,1,0,HID,128><<<dim3(DIMC / 64, NROWS / 128), 256, 0, stream>>>(
        hid, w2T, b2, xm2, out, DIMC);
}